// Round 8
// baseline (131.614 us; speedup 1.0000x reference)
//
#include <hip/hip_runtime.h>
#include <math.h>

#define H 4
#define HD 64
#define NN 1024
#define BB 8
#define FIN 256
#define FOUT 256

typedef _Float16 f16x8 __attribute__((ext_vector_type(8)));
typedef _Float16 f16x4 __attribute__((ext_vector_type(4)));
typedef _Float16 f16x2 __attribute__((ext_vector_type(2)));
typedef float f32x4 __attribute__((ext_vector_type(4)));

// ---------------------------------------------------------------------------
// Kernel 0: prep. Blocks 0..1023: pack adj -> 1 bit/edge (streaming).
// Blocks 1024..1039: WT[f][k] = (fp16) W[k][f] in 64x64 tiles.
// ---------------------------------------------------------------------------
__global__ __launch_bounds__(256) void prep(const int* __restrict__ adj,
                                            unsigned* __restrict__ adjP,
                                            const float* __restrict__ W,
                                            _Float16* __restrict__ WT) {
  __shared__ float tile[64][68];
  const int tid = threadIdx.x;
  if (blockIdx.x < 1024) {
    size_t widx = (size_t)blockIdx.x * 256 + tid;  // [0, 8*1024*32)
    const int4* p = (const int4*)adj + widx * 8;
    int4 v[8];
#pragma unroll
    for (int i = 0; i < 8; ++i) v[i] = p[i];
    unsigned bits = 0;
#pragma unroll
    for (int i = 0; i < 8; ++i) {
      bits |= (v[i].x != 0 ? 1u : 0u) << (4 * i);
      bits |= (v[i].y != 0 ? 2u : 0u) << (4 * i);
      bits |= (v[i].z != 0 ? 4u : 0u) << (4 * i);
      bits |= (v[i].w != 0 ? 8u : 0u) << (4 * i);
    }
    adjP[widx] = bits;
  } else {
    const int bx = blockIdx.x - 1024;
    const int k0 = (bx & 3) * 64, f0 = (bx >> 2) * 64;
    const int r = tid >> 4, c4 = (tid & 15) * 4;
#pragma unroll
    for (int p = 0; p < 4; ++p) {
      float4 v = *(const float4*)&W[(size_t)(k0 + p * 16 + r) * FOUT + f0 + c4];
      *(float4*)&tile[p * 16 + r][c4] = v;
    }
    __syncthreads();
    const int f = tid >> 2, kg = (tid & 3) * 16;
#pragma unroll
    for (int i = 0; i < 4; ++i) {
      f16x4 o;
#pragma unroll
      for (int j = 0; j < 4; ++j) o[j] = (_Float16)tile[kg + i * 4 + j][f];
      *(f16x4*)&WT[(size_t)(f0 + f) * FIN + k0 + kg + i * 4] = o;
    }
  }
}

// ---------------------------------------------------------------------------
// Kernel 1: h = x @ W via fp16 MFMA. Block = 64 rows x 1 head, 512 blocks.
// W tile staged ONCE to LDS (one barrier); A-frags read directly from global
// x (2 coalesced float4/lane/ks) -> waves fully independent in the K loop.
// Epilogue fuses scores: s1, s2, u=exp(s2), v=exp(0.2*s2).
// ---------------------------------------------------------------------------
__global__ __launch_bounds__(256) void gemm_xw(const float* __restrict__ x,
                                               const _Float16* __restrict__ WT,
                                               const float* __restrict__ a,
                                               _Float16* __restrict__ hT,
                                               float* __restrict__ s1_ws,
                                               float* __restrict__ s2_ws,
                                               float* __restrict__ u_ws,
                                               float* __restrict__ v_ws) {
  __shared__ _Float16 wl[64][264];  // head's W^T tile [f'][k], stride 528B
  const int tid = threadIdx.x;
  const int lane = tid & 63, w = tid >> 6;
  const int c = lane & 15, q = lane >> 4;
  const int bn0 = blockIdx.x * 64;
  const int head = blockIdx.y;
  const int b = bn0 >> 10, nb = bn0 & 1023;
  const int bh = b * H + head;

  // stage W^T tile (64 f' x 256 k fp16 = 32KB), coalesced b128
  {
    const int row = tid >> 2, kseg = (tid & 3) * 64;
    const _Float16* wp = WT + (size_t)(head * 64 + row) * FIN + kseg;
#pragma unroll
    for (int i = 0; i < 8; ++i) {
      f16x8 t = *(const f16x8*)(wp + i * 8);
      *(f16x8*)&wl[row][kseg + i * 8] = t;
    }
  }
  __syncthreads();

  f32x4 acc[4];
#pragma unroll
  for (int t = 0; t < 4; ++t) acc[t] = (f32x4){0.f, 0.f, 0.f, 0.f};
  const float* xp = x + (size_t)(bn0 + w * 16 + c) * FIN + q * 8;
#pragma unroll
  for (int ks = 0; ks < 8; ++ks) {
    float4 xa = *(const float4*)(xp + ks * 32);
    float4 xb = *(const float4*)(xp + ks * 32 + 4);
    f16x8 af;
    af[0] = (_Float16)xa.x; af[1] = (_Float16)xa.y;
    af[2] = (_Float16)xa.z; af[3] = (_Float16)xa.w;
    af[4] = (_Float16)xb.x; af[5] = (_Float16)xb.y;
    af[6] = (_Float16)xb.z; af[7] = (_Float16)xb.w;
#pragma unroll
    for (int t = 0; t < 4; ++t) {
      f16x8 bf = *(const f16x8*)&wl[t * 16 + c][ks * 32 + q * 8];
      acc[t] = __builtin_amdgcn_mfma_f32_16x16x32_f16(af, bf, acc[t], 0, 0, 0);
    }
  }

  // epilogue: lane holds rows n = w*16 + q*4 + rr, cols f = t*16 + c
  float a1v[4], a2v[4];
#pragma unroll
  for (int t = 0; t < 4; ++t) {
    a1v[t] = a[head * 2 * HD + t * 16 + c];
    a2v[t] = a[head * 2 * HD + HD + t * 16 + c];
  }
  float s1p[4] = {0.f, 0.f, 0.f, 0.f};
  float s2p[4] = {0.f, 0.f, 0.f, 0.f};
#pragma unroll
  for (int t = 0; t < 4; ++t) {
    f16x4 hv;
#pragma unroll
    for (int rr = 0; rr < 4; ++rr) {
      hv[rr] = (_Float16)acc[t][rr];
      s1p[rr] += acc[t][rr] * a1v[t];
      s2p[rr] += acc[t][rr] * a2v[t];
    }
    *(f16x4*)&hT[((size_t)(bh * 64 + t * 16 + c)) * NN + nb + w * 16 + q * 4] = hv;
  }
#pragma unroll
  for (int rr = 0; rr < 4; ++rr) {
    float s1 = s1p[rr], s2 = s2p[rr];
#pragma unroll
    for (int off = 8; off; off >>= 1) {
      s1 += __shfl_xor(s1, off);
      s2 += __shfl_xor(s2, off);
    }
    if (c == 0) {
      int n = nb + w * 16 + q * 4 + rr;
      size_t idx = (size_t)bh * NN + n;
      s1_ws[idx] = s1;
      s2_ws[idx] = s2;
      u_ws[idx] = __expf(s2);
      v_ws[idx] = __expf(0.2f * s2);
    }
  }
}

// ---------------------------------------------------------------------------
// Kernel 2: attention, BARRIER-FREE main loop. Block = 64 n-rows x (b,h);
// 512 blocks, 4 independent waves (wave wv owns rows wv*16..+15).
// Each lane computes its MFMA A-frag elements DIRECTLY (row=c, k=q*8+j):
// p = (s1+s2>=0) ? Arow*u[m] : Brow*v[m], masked by packed adj bits.
// No P round-trip through LDS, no inner barriers; s2/u/v/masks are LDS
// broadcast reads; B-frags (hT) prefetched one chunk ahead from L2.
// ---------------------------------------------------------------------------
__global__ __launch_bounds__(256) void attn(const _Float16* __restrict__ hT,
                                            const float* __restrict__ s1_ws,
                                            const float* __restrict__ s2_ws,
                                            const float* __restrict__ u_ws,
                                            const float* __restrict__ v_ws,
                                            const unsigned* __restrict__ adjP,
                                            float* __restrict__ out) {
  __shared__ float s2r[NN], uu[NN], vv[NN];  // 12 KB
  __shared__ unsigned adjW[64][32];          // 8 KB packed mask (row-major)
  const int tid = threadIdx.x, lane = tid & 63, wv = tid >> 6;
  const int c = lane & 15, q = lane >> 4;
  const int ntile = blockIdx.x, bh = blockIdx.y;
  const int b = bh >> 2, head = bh & 3;
  const int n0 = ntile * 64;
  const int myrow = wv * 16 + c;  // this lane's P/A row (block-local)

  {
    size_t base = (size_t)bh * NN + tid * 4;
    *(float4*)&s2r[tid * 4] = *(const float4*)&s2_ws[base];
    *(float4*)&uu[tid * 4] = *(const float4*)&u_ws[base];
    *(float4*)&vv[tid * 4] = *(const float4*)&v_ws[base];
    const int row = tid >> 2, wo = (tid & 3) * 8;
    const uint4* ap = (const uint4*)(adjP + ((size_t)(b * NN + n0 + row)) * 32 + wo);
    uint4 m0 = ap[0], m1 = ap[1];
    *(uint4*)&adjW[row][wo] = m0;
    *(uint4*)&adjW[row][wo + 4] = m1;
  }
  __syncthreads();  // the ONLY block-wide barrier

  const float s1 = s1_ws[(size_t)bh * NN + n0 + myrow];

  // ---- pass 1: masked max of s2 over this lane's (row, m=kc*32+q*8..+7) ----
  float mx = -INFINITY;
#pragma unroll 8
  for (int kc = 0; kc < 32; ++kc) {
    unsigned byte = (adjW[myrow][kc] >> (q * 8)) & 0xffu;
    float4 sa = *(const float4*)&s2r[kc * 32 + q * 8];
    float4 sb = *(const float4*)&s2r[kc * 32 + q * 8 + 4];
    mx = fmaxf(mx, (byte & 1u) ? sa.x : -INFINITY);
    mx = fmaxf(mx, (byte & 2u) ? sa.y : -INFINITY);
    mx = fmaxf(mx, (byte & 4u) ? sa.z : -INFINITY);
    mx = fmaxf(mx, (byte & 8u) ? sa.w : -INFINITY);
    mx = fmaxf(mx, (byte & 16u) ? sb.x : -INFINITY);
    mx = fmaxf(mx, (byte & 32u) ? sb.y : -INFINITY);
    mx = fmaxf(mx, (byte & 64u) ? sb.z : -INFINITY);
    mx = fmaxf(mx, (byte & 128u) ? sb.w : -INFINITY);
  }
  mx = fmaxf(mx, __shfl_xor(mx, 16));
  mx = fmaxf(mx, __shfl_xor(mx, 32));
  const float t0 = s1 + mx;
  const float M = fmaxf(t0, 0.2f * t0);  // lrelu (monotone => exact row max)
  const float Ar = __expf(s1 - M), Br = __expf(0.2f * s1 - M), ns1 = -s1;

  // ---- pass 2: A-frags computed in-register, 4 MFMA per 32-m chunk ----
  f32x4 acc[4];
#pragma unroll
  for (int t = 0; t < 4; ++t) acc[t] = (f32x4){0.f, 0.f, 0.f, 0.f};
  float psum = 0.f;
  const _Float16* bp0 = hT + ((size_t)bh * 64 + c) * NN + q * 8;

  f16x8 nbf[4];
#pragma unroll
  for (int t = 0; t < 4; ++t) nbf[t] = *(const f16x8*)(bp0 + (size_t)t * 16 * NN);

#pragma unroll 4
  for (int kc = 0; kc < 32; ++kc) {
    f16x8 bf[4];
#pragma unroll
    for (int t = 0; t < 4; ++t) bf[t] = nbf[t];
    unsigned byte = (adjW[myrow][kc] >> (q * 8)) & 0xffu;
    float4 sa = *(const float4*)&s2r[kc * 32 + q * 8];
    float4 sb = *(const float4*)&s2r[kc * 32 + q * 8 + 4];
    float4 ua = *(const float4*)&uu[kc * 32 + q * 8];
    float4 ub = *(const float4*)&uu[kc * 32 + q * 8 + 4];
    float4 va = *(const float4*)&vv[kc * 32 + q * 8];
    float4 vb = *(const float4*)&vv[kc * 32 + q * 8 + 4];
    float p0 = (sa.x >= ns1) ? Ar * ua.x : Br * va.x;
    float p1 = (sa.y >= ns1) ? Ar * ua.y : Br * va.y;
    float p2 = (sa.z >= ns1) ? Ar * ua.z : Br * va.z;
    float p3 = (sa.w >= ns1) ? Ar * ua.w : Br * va.w;
    float p4 = (sb.x >= ns1) ? Ar * ub.x : Br * vb.x;
    float p5 = (sb.y >= ns1) ? Ar * ub.y : Br * vb.y;
    float p6 = (sb.z >= ns1) ? Ar * ub.z : Br * vb.z;
    float p7 = (sb.w >= ns1) ? Ar * ub.w : Br * vb.w;
    p0 = (byte & 1u) ? p0 : 0.f;
    p1 = (byte & 2u) ? p1 : 0.f;
    p2 = (byte & 4u) ? p2 : 0.f;
    p3 = (byte & 8u) ? p3 : 0.f;
    p4 = (byte & 16u) ? p4 : 0.f;
    p5 = (byte & 32u) ? p5 : 0.f;
    p6 = (byte & 64u) ? p6 : 0.f;
    p7 = (byte & 128u) ? p7 : 0.f;
    psum += ((p0 + p1) + (p2 + p3)) + ((p4 + p5) + (p6 + p7));
    union { f16x8 v8; f16x2 v2[4]; } au;
    au.v2[0] = __builtin_bit_cast(f16x2, __builtin_amdgcn_cvt_pkrtz(p0, p1));
    au.v2[1] = __builtin_bit_cast(f16x2, __builtin_amdgcn_cvt_pkrtz(p2, p3));
    au.v2[2] = __builtin_bit_cast(f16x2, __builtin_amdgcn_cvt_pkrtz(p4, p5));
    au.v2[3] = __builtin_bit_cast(f16x2, __builtin_amdgcn_cvt_pkrtz(p6, p7));
    if (kc < 31) {
#pragma unroll
      for (int t = 0; t < 4; ++t)
        nbf[t] = *(const f16x8*)(bp0 + (size_t)t * 16 * NN + (kc + 1) * 32);
    }
#pragma unroll
    for (int t = 0; t < 4; ++t)
      acc[t] = __builtin_amdgcn_mfma_f32_16x16x32_f16(au.v8, bf[t], acc[t], 0, 0, 0);
  }

  // ---- epilogue: L reduce + redistribute to D-frag rows ----
  psum += __shfl_xor(psum, 16);
  psum += __shfl_xor(psum, 32);  // L for row myrow, valid in all lanes w/ same c
  float il[4];
#pragma unroll
  for (int rr = 0; rr < 4; ++rr) il[rr] = 1.0f / __shfl(psum, q * 4 + rr);
#pragma unroll
  for (int t = 0; t < 4; ++t) {
#pragma unroll
    for (int rr = 0; rr < 4; ++rr) {
      out[((size_t)(b * NN + n0 + wv * 16 + q * 4 + rr)) * FOUT + head * 64 + t * 16 + c] =
          acc[t][rr] * il[rr];
    }
  }
}

extern "C" void kernel_launch(void* const* d_in, const int* in_sizes, int n_in,
                              void* d_out, int out_size, void* d_ws, size_t ws_size,
                              hipStream_t stream) {
  const float* x = (const float*)d_in[0];
  const int* adj = (const int*)d_in[1];
  const float* W = (const float*)d_in[2];
  const float* a = (const float*)d_in[3];
  float* out = (float*)d_out;

  char* ws = (char*)d_ws;
  _Float16* hT = (_Float16*)ws;                              // 4 MB
  _Float16* WT = (_Float16*)(ws + (size_t)4 * 1024 * 1024);  // 128 KB
  float* s1_ws = (float*)(ws + (size_t)4 * 1024 * 1024 + 128 * 1024);
  float* s2_ws = s1_ws + (size_t)BB * H * NN;
  float* u_ws = s2_ws + (size_t)BB * H * NN;
  float* v_ws = u_ws + (size_t)BB * H * NN;
  unsigned* adjP = (unsigned*)(v_ws + (size_t)BB * H * NN);  // 1 MB

  prep<<<1040, 256, 0, stream>>>(adj, adjP, W, WT);
  gemm_xw<<<dim3(128, 4), 256, 0, stream>>>(x, WT, a, hT, s1_ws, s2_ws, u_ws, v_ws);
  attn<<<dim3(16, 32), 256, 0, stream>>>(hT, s1_ws, s2_ws, u_ws, v_ws, adjP, out);
}

// Round 9
// 120.335 us; speedup vs baseline: 1.0937x; 1.0937x over previous
//
#include <hip/hip_runtime.h>
#include <math.h>

#define H 4
#define HD 64
#define NN 1024
#define BB 8
#define FIN 256
#define FOUT 256

typedef _Float16 f16x8 __attribute__((ext_vector_type(8)));
typedef _Float16 f16x4 __attribute__((ext_vector_type(4)));
typedef _Float16 f16x2 __attribute__((ext_vector_type(2)));
typedef float f32x4 __attribute__((ext_vector_type(4)));

__device__ __forceinline__ unsigned fkey(float f) {
  unsigned u = __float_as_uint(f);
  return (u & 0x80000000u) ? ~u : (u | 0x80000000u);
}
__device__ __forceinline__ float fdecode(unsigned k) {
  unsigned u = (k & 0x80000000u) ? (k & 0x7fffffffu) : ~k;
  return __uint_as_float(u);
}

// ---------------------------------------------------------------------------
// Kernel 0: prep. Blocks 0..1023: pack adj -> 1 bit/edge (streaming).
// Blocks 1024..1039: WT[f][k] = (fp16) W[k][f]; block 1024 also zeroes S2maxU.
// ---------------------------------------------------------------------------
__global__ __launch_bounds__(256) void prep(const int* __restrict__ adj,
                                            unsigned* __restrict__ adjP,
                                            const float* __restrict__ W,
                                            _Float16* __restrict__ WT,
                                            unsigned* __restrict__ S2maxU) {
  __shared__ float tile[64][68];
  const int tid = threadIdx.x;
  if (blockIdx.x < 1024) {
    size_t widx = (size_t)blockIdx.x * 256 + tid;  // [0, 8*1024*32)
    const int4* p = (const int4*)adj + widx * 8;
    int4 v[8];
#pragma unroll
    for (int i = 0; i < 8; ++i) v[i] = p[i];
    unsigned bits = 0;
#pragma unroll
    for (int i = 0; i < 8; ++i) {
      bits |= (v[i].x != 0 ? 1u : 0u) << (4 * i);
      bits |= (v[i].y != 0 ? 2u : 0u) << (4 * i);
      bits |= (v[i].z != 0 ? 4u : 0u) << (4 * i);
      bits |= (v[i].w != 0 ? 8u : 0u) << (4 * i);
    }
    adjP[widx] = bits;
  } else {
    if (blockIdx.x == 1024 && tid < 32) S2maxU[tid] = 0u;
    const int bx = blockIdx.x - 1024;
    const int k0 = (bx & 3) * 64, f0 = (bx >> 2) * 64;
    const int r = tid >> 4, c4 = (tid & 15) * 4;
#pragma unroll
    for (int p = 0; p < 4; ++p) {
      float4 v = *(const float4*)&W[(size_t)(k0 + p * 16 + r) * FOUT + f0 + c4];
      *(float4*)&tile[p * 16 + r][c4] = v;
    }
    __syncthreads();
    const int f = tid >> 2, kg = (tid & 3) * 16;
#pragma unroll
    for (int i = 0; i < 4; ++i) {
      f16x4 o;
#pragma unroll
      for (int j = 0; j < 4; ++j) o[j] = (_Float16)tile[kg + i * 4 + j][f];
      *(f16x4*)&WT[(size_t)(f0 + f) * FIN + k0 + kg + i * 4] = o;
    }
  }
}

// ---------------------------------------------------------------------------
// Kernel 1: h = x @ W via fp16 MFMA (r7 structure, validated). Epilogue
// stores s1, s2 and per-(b,h) atomicMax of s2 (ordered-uint key).
// ---------------------------------------------------------------------------
__global__ __launch_bounds__(256) void gemm_xw(const float* __restrict__ x,
                                               const _Float16* __restrict__ WT,
                                               const float* __restrict__ a,
                                               _Float16* __restrict__ hT,
                                               float* __restrict__ s1_ws,
                                               float* __restrict__ s2_ws,
                                               unsigned* __restrict__ S2maxU) {
  __shared__ _Float16 wl[64][264];
  const int tid = threadIdx.x;
  const int lane = tid & 63, w = tid >> 6;
  const int c = lane & 15, q = lane >> 4;
  const int bn0 = blockIdx.x * 64;
  const int head = blockIdx.y;
  const int b = bn0 >> 10, nb = bn0 & 1023;
  const int bh = b * H + head;

  {
    const int row = tid >> 2, kseg = (tid & 3) * 64;
    const _Float16* wp = WT + (size_t)(head * 64 + row) * FIN + kseg;
#pragma unroll
    for (int i = 0; i < 8; ++i) {
      f16x8 t = *(const f16x8*)(wp + i * 8);
      *(f16x8*)&wl[row][kseg + i * 8] = t;
    }
  }
  __syncthreads();

  f32x4 acc[4];
#pragma unroll
  for (int t = 0; t < 4; ++t) acc[t] = (f32x4){0.f, 0.f, 0.f, 0.f};
  const float* xp = x + (size_t)(bn0 + w * 16 + c) * FIN + q * 8;
#pragma unroll
  for (int ks = 0; ks < 8; ++ks) {
    float4 xa = *(const float4*)(xp + ks * 32);
    float4 xb = *(const float4*)(xp + ks * 32 + 4);
    f16x8 af;
    af[0] = (_Float16)xa.x; af[1] = (_Float16)xa.y;
    af[2] = (_Float16)xa.z; af[3] = (_Float16)xa.w;
    af[4] = (_Float16)xb.x; af[5] = (_Float16)xb.y;
    af[6] = (_Float16)xb.z; af[7] = (_Float16)xb.w;
#pragma unroll
    for (int t = 0; t < 4; ++t) {
      f16x8 bf = *(const f16x8*)&wl[t * 16 + c][ks * 32 + q * 8];
      acc[t] = __builtin_amdgcn_mfma_f32_16x16x32_f16(af, bf, acc[t], 0, 0, 0);
    }
  }

  float a1v[4], a2v[4];
#pragma unroll
  for (int t = 0; t < 4; ++t) {
    a1v[t] = a[head * 2 * HD + t * 16 + c];
    a2v[t] = a[head * 2 * HD + HD + t * 16 + c];
  }
  float s1p[4] = {0.f, 0.f, 0.f, 0.f};
  float s2p[4] = {0.f, 0.f, 0.f, 0.f};
#pragma unroll
  for (int t = 0; t < 4; ++t) {
    f16x4 hv;
#pragma unroll
    for (int rr = 0; rr < 4; ++rr) {
      hv[rr] = (_Float16)acc[t][rr];
      s1p[rr] += acc[t][rr] * a1v[t];
      s2p[rr] += acc[t][rr] * a2v[t];
    }
    *(f16x4*)&hT[((size_t)(bh * 64 + t * 16 + c)) * NN + nb + w * 16 + q * 4] = hv;
  }
  float ms2 = -INFINITY;
#pragma unroll
  for (int rr = 0; rr < 4; ++rr) {
    float s1 = s1p[rr], s2 = s2p[rr];
#pragma unroll
    for (int off = 8; off; off >>= 1) {  // butterfly over c: all lanes get value
      s1 += __shfl_xor(s1, off);
      s2 += __shfl_xor(s2, off);
    }
    ms2 = fmaxf(ms2, s2);
    if (c == 0) {
      int n = nb + w * 16 + q * 4 + rr;
      size_t idx = (size_t)bh * NN + n;
      s1_ws[idx] = s1;
      s2_ws[idx] = s2;
    }
  }
  ms2 = fmaxf(ms2, __shfl_xor(ms2, 16));
  ms2 = fmaxf(ms2, __shfl_xor(ms2, 32));
  if (lane == 0) atomicMax(&S2maxU[bh], fkey(ms2));
}

// ---------------------------------------------------------------------------
// Kernel 2: attention. Block = 64 rows x (b,h), 512 blocks, 4 waves.
// Wave wv owns d-slice wv*16..+15 -> each hT byte read once per block.
// p = max(Ar*u, Br*v) (lrelu's max commutes through exp): no s2 in the loop,
// no per-row masked max (M = lrelu(s1 + S2max_bh) upper bound, exact on dense).
// u,v fp16 in LDS (1 b128 each per kc); packed fp16 p-math; L via a 5th MFMA
// against a ones-column B. Dense fast path skips all mask work.
// ---------------------------------------------------------------------------
__global__ __launch_bounds__(256) void attn(const _Float16* __restrict__ hT,
                                            const float* __restrict__ s1_ws,
                                            const float* __restrict__ s2_ws,
                                            const unsigned* __restrict__ S2maxU,
                                            const unsigned* __restrict__ adjP,
                                            float* __restrict__ out) {
  __shared__ _Float16 u16[NN], v16[NN];  // 4 KB
  __shared__ unsigned adjW[64][36];      // 9.2 KB, padded (row start 16B-mult)
  __shared__ int denseFlag;
  const int tid = threadIdx.x, lane = tid & 63, wv = tid >> 6;
  const int c = lane & 15, q = lane >> 4;
  const int ntile = blockIdx.x, bh = blockIdx.y;
  const int b = bh >> 2, head = bh & 3;
  const int n0 = ntile * 64;

  if (tid == 0) denseFlag = 1;
  __syncthreads();

  const float S2 = fdecode(S2maxU[bh]);
  {
    float4 s2a = *(const float4*)&s2_ws[(size_t)bh * NN + tid * 4];
    f16x4 ua, va;
    ua[0] = (_Float16)__expf(s2a.x - S2); va[0] = (_Float16)__expf(0.2f * (s2a.x - S2));
    ua[1] = (_Float16)__expf(s2a.y - S2); va[1] = (_Float16)__expf(0.2f * (s2a.y - S2));
    ua[2] = (_Float16)__expf(s2a.z - S2); va[2] = (_Float16)__expf(0.2f * (s2a.z - S2));
    ua[3] = (_Float16)__expf(s2a.w - S2); va[3] = (_Float16)__expf(0.2f * (s2a.w - S2));
    *(f16x4*)&u16[tid * 4] = ua;
    *(f16x4*)&v16[tid * 4] = va;
    const int row = tid >> 2, wo = (tid & 3) * 8;
    const uint4* ap = (const uint4*)(adjP + ((size_t)(b * NN + n0 + row)) * 32 + wo);
    uint4 m0 = ap[0], m1 = ap[1];
    *(uint4*)&adjW[row][wo] = m0;
    *(uint4*)&adjW[row][wo + 4] = m1;
    unsigned andall = m0.x & m0.y & m0.z & m0.w & m1.x & m1.y & m1.z & m1.w;
    if (andall != 0xffffffffu) atomicAnd(&denseFlag, 0);
  }
  __syncthreads();
  const int dense = denseFlag;

  // per-row scalars for the 4 row-groups (row = g*16 + c)
  f16x2 ar2[4], br2[4];
#pragma unroll
  for (int g = 0; g < 4; ++g) {
    float s1 = s1_ws[(size_t)bh * NN + n0 + g * 16 + c];
    float t = s1 + S2;
    float M = fmaxf(t, 0.2f * t);
    _Float16 A = (_Float16)__expf(t - M);
    _Float16 Bv = (_Float16)__expf(0.2f * t - M);
    ar2[g][0] = A; ar2[g][1] = A;
    br2[g][0] = Bv; br2[g][1] = Bv;
  }

  f32x4 acc[4], accL[4];
#pragma unroll
  for (int g = 0; g < 4; ++g) {
    acc[g] = (f32x4){0.f, 0.f, 0.f, 0.f};
    accL[g] = (f32x4){0.f, 0.f, 0.f, 0.f};
  }
  // ones-column B: B[k][0] = 1 -> lanes with c==0 hold 1
  f16x8 bones;
  {
    _Float16 o = (c == 0) ? (_Float16)1.0f : (_Float16)0.0f;
#pragma unroll
    for (int j = 0; j < 8; ++j) bones[j] = o;
  }

  const _Float16* bp = hT + ((size_t)bh * 64 + wv * 16 + c) * NN + q * 8;
  f16x8 nbf = *(const f16x8*)bp;

  for (int kc4 = 0; kc4 < 8; ++kc4) {
    unsigned mrow[4][4];
    if (!dense) {
#pragma unroll
      for (int g = 0; g < 4; ++g) {
        uint4 t = *(const uint4*)&adjW[g * 16 + c][kc4 * 4];
        mrow[g][0] = t.x; mrow[g][1] = t.y; mrow[g][2] = t.z; mrow[g][3] = t.w;
      }
    }
#pragma unroll
    for (int kk = 0; kk < 4; ++kk) {
      const int kc = kc4 * 4 + kk;
      f16x8 bf = nbf;
      if (kc < 31) nbf = *(const f16x8*)(bp + (kc + 1) * 32);
      f16x8 u8 = *(const f16x8*)&u16[kc * 32 + q * 8];
      f16x8 v8 = *(const f16x8*)&v16[kc * 32 + q * 8];
      f16x2 up[4], vp[4];
#pragma unroll
      for (int j = 0; j < 4; ++j) {
        up[j][0] = u8[2 * j]; up[j][1] = u8[2 * j + 1];
        vp[j][0] = v8[2 * j]; vp[j][1] = v8[2 * j + 1];
      }
#pragma unroll
      for (int g = 0; g < 4; ++g) {
        f16x2 pp[4];
#pragma unroll
        for (int j = 0; j < 4; ++j)
          pp[j] = __builtin_elementwise_max(ar2[g] * up[j], br2[g] * vp[j]);
        if (!dense) {
          unsigned byte = (mrow[g][kk] >> (q * 8)) & 0xffu;
#pragma unroll
          for (int j = 0; j < 4; ++j) {
            unsigned pm = __builtin_bit_cast(unsigned, pp[j]);
            unsigned msk = (((byte >> (2 * j)) & 1u) ? 0x0000ffffu : 0u) |
                           (((byte >> (2 * j + 1)) & 1u) ? 0xffff0000u : 0u);
            pp[j] = __builtin_bit_cast(f16x2, pm & msk);
          }
        }
        union { f16x8 v8_; f16x2 v2_[4]; } au;
        au.v2_[0] = pp[0]; au.v2_[1] = pp[1]; au.v2_[2] = pp[2]; au.v2_[3] = pp[3];
        acc[g] = __builtin_amdgcn_mfma_f32_16x16x32_f16(au.v8_, bf, acc[g], 0, 0, 0);
        accL[g] = __builtin_amdgcn_mfma_f32_16x16x32_f16(au.v8_, bones, accL[g], 0, 0, 0);
      }
    }
  }

  // epilogue: L[row g*16 + q*4 + rr] sits in lane (q*16) register rr of accL[g]
#pragma unroll
  for (int g = 0; g < 4; ++g) {
#pragma unroll
    for (int rr = 0; rr < 4; ++rr) {
      float Lrow = __shfl(accL[g][rr], q * 16);
      out[((size_t)(b * NN + n0 + g * 16 + q * 4 + rr)) * FOUT + head * 64 + wv * 16 + c] =
          acc[g][rr] / Lrow;
    }
  }
}

extern "C" void kernel_launch(void* const* d_in, const int* in_sizes, int n_in,
                              void* d_out, int out_size, void* d_ws, size_t ws_size,
                              hipStream_t stream) {
  const float* x = (const float*)d_in[0];
  const int* adj = (const int*)d_in[1];
  const float* W = (const float*)d_in[2];
  const float* a = (const float*)d_in[3];
  float* out = (float*)d_out;

  char* ws = (char*)d_ws;
  _Float16* hT = (_Float16*)ws;                              // 4 MB
  _Float16* WT = (_Float16*)(ws + (size_t)4 * 1024 * 1024);  // 128 KB
  float* s1_ws = (float*)(ws + (size_t)4 * 1024 * 1024 + 128 * 1024);
  float* s2_ws = s1_ws + (size_t)BB * H * NN;
  unsigned* S2maxU = (unsigned*)(s2_ws + (size_t)BB * H * NN);  // 32 u32
  unsigned* adjP = S2maxU + 64;                                 // 1 MB

  prep<<<1040, 256, 0, stream>>>(adj, adjP, W, WT, S2maxU);
  gemm_xw<<<dim3(128, 4), 256, 0, stream>>>(x, WT, a, hT, s1_ws, s2_ws, S2maxU);
  attn<<<dim3(16, 32), 256, 0, stream>>>(hT, s1_ws, s2_ws, S2maxU, adjP, out);
}